// Round 5
// baseline (250.022 us; speedup 1.0000x reference)
//
#include <hip/hip_runtime.h>
#include <hip/hip_bf16.h>
#include <stdint.h>

#define B_ROWS 4096
#define D_DIM  512
#define N2     8192
#define NBLK   64                         // 8192 / 128
#define NTRI   (NBLK * (NBLK + 1) / 2)    // 2080 upper-tri blocks (2080 % 8 == 0)
#define BK     64

typedef __attribute__((ext_vector_type(8))) short  bf16x8;
typedef __attribute__((ext_vector_type(4))) float  f32x4;
typedef __attribute__((ext_vector_type(8))) ushort u16x8;

// ---------------------------------------------------------------------------
// Kernel 1: wave-per-row L2-normalize + cast to bf16. Zeroes denom + counter.
// 2048 blocks x 256 threads; each wave owns one row (64 lanes x 8 floats).
// ---------------------------------------------------------------------------
__global__ __launch_bounds__(256) void normalize_kernel(const float* __restrict__ zi,
                                                        const float* __restrict__ zj,
                                                        ushort* __restrict__ zn,
                                                        float* __restrict__ denom,
                                                        unsigned int* __restrict__ counter) {
    const int t    = threadIdx.x;
    const int lane = t & 63;
    const int row  = blockIdx.x * 4 + (t >> 6);
    if (blockIdx.x == 0 && t == 0) *counter = 0u;
    if (lane == 0) denom[row] = 0.0f;

    const float* src = (row < B_ROWS) ? (zi + (size_t)row * D_DIM)
                                      : (zj + (size_t)(row - B_ROWS) * D_DIM);
    const float4 v0 = ((const float4*)src)[lane * 2 + 0];
    const float4 v1 = ((const float4*)src)[lane * 2 + 1];
    float ss = v0.x*v0.x + v0.y*v0.y + v0.z*v0.z + v0.w*v0.w
             + v1.x*v1.x + v1.y*v1.y + v1.z*v1.z + v1.w*v1.w;
    #pragma unroll
    for (int off = 1; off < 64; off <<= 1) ss += __shfl_xor(ss, off);
    const float inv = 1.0f / sqrtf(ss);   // norms ~22.6 >> eps

    float vv[8] = {v0.x, v0.y, v0.z, v0.w, v1.x, v1.y, v1.z, v1.w};
    u16x8 h;
    #pragma unroll
    for (int j = 0; j < 8; ++j) {
        __hip_bfloat16 b = __float2bfloat16(vv[j] * inv);
        h[j] = *(ushort*)&b;
    }
    *((u16x8*)(zn + (size_t)row * D_DIM + lane * 8)) = h;
}

// ---------------------------------------------------------------------------
// Kernel 2: upper-tri blocks of S = Zn*Zn^T (bf16 MFMA, BK=64), fused
// exp / diag-mask / positives / row+col sums (symmetry), last-block loss.
// 128x128 tile, 4 waves (2x2 of 64x64). LDS XOR-swizzled (rule #21: linear
// gload_lds dest + pre-swizzled global source + swizzled ds_read).
// ---------------------------------------------------------------------------
__global__ __launch_bounds__(256) void gram_kernel(const ushort* __restrict__ zn,
                                                   float* __restrict__ denom,
                                                   float* __restrict__ pos,
                                                   unsigned int* __restrict__ counter,
                                                   float* __restrict__ out) {
    __shared__ ushort As[128 * BK];   // 16 KB
    __shared__ ushort Bs[128 * BK];   // 16 KB

    const int t    = threadIdx.x;
    const int lane = t & 63;
    const int wave = t >> 6;
    const int wr   = wave >> 1;
    const int wc   = wave & 1;

    // XCD-chunked bijective swizzle (2080 = 8 * 260), then tri-decode (bx<=by)
    const int g   = blockIdx.x;
    const int bid = (g & 7) * (NTRI / 8) + (g >> 3);
    int by = (int)((sqrtf(8.0f * (float)bid + 1.0f) - 1.0f) * 0.5f);
    while ((by * (by + 1)) / 2 > bid) --by;
    while (((by + 1) * (by + 2)) / 2 <= bid) ++by;
    const int bx = bid - (by * (by + 1)) / 2;
    const int row0 = bx * 128;
    const int col0 = by * 128;
    const bool offdiag = (bx != by);

    // staging geometry: thread t writes LDS bytes [t*16 + s*4096); that is
    // (row_o = t>>3 + s*32, colb_o = (t&7)*16). Source col pre-swizzled.
    const int srow  = t >> 3;                                  // 0..31
    const int scolb = ((t & 7) << 4) ^ ((srow & 7) << 4);      // swizzled byte col

    f32x4 acc[4][4];
    #pragma unroll
    for (int m = 0; m < 4; ++m)
        #pragma unroll
        for (int n = 0; n < 4; ++n)
            acc[m][n] = (f32x4){0.f, 0.f, 0.f, 0.f};

    for (int kt = 0; kt < D_DIM / BK; ++kt) {
        const int k0 = kt * BK;
        #pragma unroll
        for (int s = 0; s < 4; ++s) {
            const int r = srow + s * 32;
            const ushort* gA = zn + (size_t)(row0 + r) * D_DIM + k0 + (scolb >> 1);
            const ushort* gB = zn + (size_t)(col0 + r) * D_DIM + k0 + (scolb >> 1);
            __builtin_amdgcn_global_load_lds(
                (const __attribute__((address_space(1))) void*)gA,
                (__attribute__((address_space(3))) void*)(As + (size_t)t * 8 + s * 2048),
                16, 0, 0);
            __builtin_amdgcn_global_load_lds(
                (const __attribute__((address_space(1))) void*)gB,
                (__attribute__((address_space(3))) void*)(Bs + (size_t)t * 8 + s * 2048),
                16, 0, 0);
        }
        __syncthreads();

        bf16x8 af[4][2], bfm[4][2];
        #pragma unroll
        for (int m = 0; m < 4; ++m) {
            const int row = wr * 64 + m * 16 + (lane & 15);
            #pragma unroll
            for (int kk = 0; kk < 2; ++kk) {
                const int colb = kk * 64 + ((lane >> 4) << 4);
                af[m][kk] = *(const bf16x8*)((const char*)As + row * 128 + (colb ^ ((row & 7) << 4)));
            }
        }
        #pragma unroll
        for (int n = 0; n < 4; ++n) {
            const int row = wc * 64 + n * 16 + (lane & 15);
            #pragma unroll
            for (int kk = 0; kk < 2; ++kk) {
                const int colb = kk * 64 + ((lane >> 4) << 4);
                bfm[n][kk] = *(const bf16x8*)((const char*)Bs + row * 128 + (colb ^ ((row & 7) << 4)));
            }
        }

        #pragma unroll
        for (int kk = 0; kk < 2; ++kk)
            #pragma unroll
            for (int m = 0; m < 4; ++m)
                #pragma unroll
                for (int n = 0; n < 4; ++n)
                    acc[m][n] = __builtin_amdgcn_mfma_f32_16x16x32_bf16(af[m][kk], bfm[n][kk], acc[m][n], 0, 0, 0);
        __syncthreads();
    }

    // Epilogue: e = exp(2s) (diag masked); positives at gcol-grow==B;
    // row sums -> denom[row]; col sums -> denom[col] (off-diag blocks only).
    const int colbase = col0 + wc * 64 + (lane & 15);
    float cs[4] = {0.f, 0.f, 0.f, 0.f};
    #pragma unroll
    for (int m = 0; m < 4; ++m) {
        const int rowbase = row0 + wr * 64 + m * 16 + (lane >> 4) * 4;
        float rs[4] = {0.f, 0.f, 0.f, 0.f};
        #pragma unroll
        for (int n = 0; n < 4; ++n) {
            const int gcol = colbase + n * 16;
            #pragma unroll
            for (int j = 0; j < 4; ++j) {
                const int grow = rowbase + j;
                const float s2 = 2.0f * acc[m][n][j];   // sim / T,  T = 0.5
                const float e  = (grow == gcol) ? 0.0f : __expf(s2);
                if (gcol - grow == B_ROWS) {            // +B diagonal, once per pair
                    __hip_atomic_store(&pos[grow], s2, __ATOMIC_RELAXED, __HIP_MEMORY_SCOPE_AGENT);
                    __hip_atomic_store(&pos[gcol], s2, __ATOMIC_RELAXED, __HIP_MEMORY_SCOPE_AGENT);
                }
                rs[j] += e;
                cs[n] += e;
            }
        }
        #pragma unroll
        for (int off = 1; off < 16; off <<= 1) {
            rs[0] += __shfl_xor(rs[0], off);
            rs[1] += __shfl_xor(rs[1], off);
            rs[2] += __shfl_xor(rs[2], off);
            rs[3] += __shfl_xor(rs[3], off);
        }
        if ((lane & 15) == 0) {
            atomicAdd(&denom[rowbase + 0], rs[0]);
            atomicAdd(&denom[rowbase + 1], rs[1]);
            atomicAdd(&denom[rowbase + 2], rs[2]);
            atomicAdd(&denom[rowbase + 3], rs[3]);
        }
    }
    if (offdiag) {
        #pragma unroll
        for (int off = 16; off < 64; off <<= 1) {
            cs[0] += __shfl_xor(cs[0], off);
            cs[1] += __shfl_xor(cs[1], off);
            cs[2] += __shfl_xor(cs[2], off);
            cs[3] += __shfl_xor(cs[3], off);
        }
        if (lane < 16) {
            atomicAdd(&denom[colbase + 0],  cs[0]);
            atomicAdd(&denom[colbase + 16], cs[1]);
            atomicAdd(&denom[colbase + 32], cs[2]);
            atomicAdd(&denom[colbase + 48], cs[3]);
        }
    }

    // ---- last block computes the loss (saves a kernel launch) ----
    __threadfence();                 // make our atomics visible device-wide
    __syncthreads();
    __shared__ unsigned int lastflag;
    if (t == 0) lastflag = (atomicAdd(counter, 1u) + 1u == (unsigned)NTRI);
    __syncthreads();
    if (lastflag) {
        __threadfence();
        float partial = 0.f;
        for (int i = t; i < N2; i += 256) {
            const float d = __hip_atomic_load(&denom[i], __ATOMIC_RELAXED, __HIP_MEMORY_SCOPE_AGENT);
            const float p = __hip_atomic_load(&pos[i],   __ATOMIC_RELAXED, __HIP_MEMORY_SCOPE_AGENT);
            partial += logf(d + 1e-8f) - p;
        }
        #pragma unroll
        for (int off = 1; off < 64; off <<= 1) partial += __shfl_xor(partial, off);
        __shared__ float red[4];
        if ((t & 63) == 0) red[t >> 6] = partial;
        __syncthreads();
        if (t == 0) out[0] = (red[0] + red[1] + red[2] + red[3]) * (1.0f / (float)N2);
    }
}

// ---------------------------------------------------------------------------
extern "C" void kernel_launch(void* const* d_in, const int* in_sizes, int n_in,
                              void* d_out, int out_size, void* d_ws, size_t ws_size,
                              hipStream_t stream) {
    const float* zi = (const float*)d_in[0];
    const float* zj = (const float*)d_in[1];
    char* ws = (char*)d_ws;
    ushort* zn            = (ushort*)ws;                           // 8 MB
    float* denom          = (float*)(ws + (size_t)N2 * D_DIM * 2); // 8192 f32
    float* pos            = denom + N2;                            // 8192 f32
    unsigned int* counter = (unsigned int*)(pos + N2);             // 1 u32
    float* out            = (float*)d_out;

    normalize_kernel<<<N2 / 4, 256, 0, stream>>>(zi, zj, zn, denom, counter);
    gram_kernel<<<NTRI, 256, 0, stream>>>(zn, denom, pos, counter, out);
}

// Round 6
// 152.322 us; speedup vs baseline: 1.6414x; 1.6414x over previous
//
#include <hip/hip_runtime.h>
#include <hip/hip_bf16.h>
#include <stdint.h>

#define B_ROWS 4096
#define D_DIM  512
#define N2     8192
#define NBLK   64          // 8192 / 128
#define NTRI   (NBLK * (NBLK + 1) / 2)   // 2080 upper-tri blocks

typedef __attribute__((ext_vector_type(8))) short bf16x8;
typedef __attribute__((ext_vector_type(4))) float f32x4;

// ---------------------------------------------------------------------------
// Kernel 1: row L2-norms, normalize, cast to bf16. Also zeroes denom[row].
// ---------------------------------------------------------------------------
__global__ void normalize_kernel(const float* __restrict__ zi,
                                 const float* __restrict__ zj,
                                 ushort* __restrict__ zn,
                                 float* __restrict__ denom) {
    const int row = blockIdx.x;         // 0..8191
    const int t   = threadIdx.x;        // 256 threads, one float2 each
    if (t == 0) denom[row] = 0.0f;
    const float* src = (row < B_ROWS) ? (zi + (size_t)row * D_DIM)
                                      : (zj + (size_t)(row - B_ROWS) * D_DIM);
    float2 v = ((const float2*)src)[t];
    float ss = v.x * v.x + v.y * v.y;
    #pragma unroll
    for (int off = 1; off < 64; off <<= 1) ss += __shfl_xor(ss, off);
    __shared__ float red[4];
    if ((t & 63) == 0) red[t >> 6] = ss;
    __syncthreads();
    const float tot = red[0] + red[1] + red[2] + red[3];
    const float inv = 1.0f / sqrtf(tot);   // norms ~22.6 >> eps
    __hip_bfloat16 hx = __float2bfloat16(v.x * inv);
    __hip_bfloat16 hy = __float2bfloat16(v.y * inv);
    ushort2 h;
    h.x = *(ushort*)&hx;
    h.y = *(ushort*)&hy;
    ((ushort2*)zn)[(size_t)row * (D_DIM / 2) + t] = h;
}

// ---------------------------------------------------------------------------
// Kernel 2: upper-triangular blocks of S = Zn*Zn^T (bf16 MFMA), fused
// exp / diag-mask / positives / row+col partial sums (symmetry exploited).
// 128x128 tile, BK=32, 4 waves (2x2 of 64x64).
// Round-6 change (isolated): double-buffered LDS with 2-phase prefetch —
// stage tile kt+1 while computing tile kt; ONE __syncthreads per K-step.
// ---------------------------------------------------------------------------
__global__ __launch_bounds__(256) void gram_kernel(const ushort* __restrict__ zn,
                                                   float* __restrict__ denom,
                                                   float* __restrict__ pos) {
    __shared__ ushort As[2][128 * 32];   // 2 x 8 KB
    __shared__ ushort Bs[2][128 * 32];   // 2 x 8 KB

    const int t    = threadIdx.x;
    const int lane = t & 63;
    const int wave = t >> 6;
    const int wr   = wave >> 1;       // wave-row quadrant (0..1)
    const int wc   = wave & 1;        // wave-col quadrant (0..1)

    // triangular index -> (bx <= by): rows = bx*128, cols = by*128
    const int bid = blockIdx.x;
    int by = (int)((sqrtf(8.0f * (float)bid + 1.0f) - 1.0f) * 0.5f);
    while ((by * (by + 1)) / 2 > bid) --by;
    while (((by + 1) * (by + 2)) / 2 <= bid) ++by;
    const int bx = bid - (by * (by + 1)) / 2;
    const int row0 = bx * 128;
    const int col0 = by * 128;
    const bool offdiag = (bx != by);

    const int srow = t >> 2;          // staging row within half (0..63)
    const int scol = (t & 3) * 8;     // staging col (ushorts)

    f32x4 acc[4][4];
    #pragma unroll
    for (int m = 0; m < 4; ++m)
        #pragma unroll
        for (int n = 0; n < 4; ++n)
            acc[m][n] = (f32x4){0.f, 0.f, 0.f, 0.f};

    const int lrow_a = wr * 64 + (lane & 15);
    const int lrow_b = wc * 64 + (lane & 15);
    const int kgrp   = (lane >> 4) * 8;

    // ---- staging helper: 4 x global_load_lds (16B) into buffer `buf` ----
    #define STAGE(buf, kt)                                                         \
        do {                                                                       \
            const int k0_ = (kt) * 32;                                             \
            _Pragma("unroll")                                                      \
            for (int half = 0; half < 2; ++half) {                                 \
                const int r_ = srow + half * 64;                                   \
                const ushort* gA_ = zn + (size_t)(row0 + r_) * D_DIM + k0_ + scol; \
                const ushort* gB_ = zn + (size_t)(col0 + r_) * D_DIM + k0_ + scol; \
                __builtin_amdgcn_global_load_lds(                                  \
                    (const __attribute__((address_space(1))) void*)gA_,            \
                    (__attribute__((address_space(3))) void*)(As[(buf)] + (size_t)(t + half * 256) * 8), \
                    16, 0, 0);                                                     \
                __builtin_amdgcn_global_load_lds(                                  \
                    (const __attribute__((address_space(1))) void*)gB_,            \
                    (__attribute__((address_space(3))) void*)(Bs[(buf)] + (size_t)(t + half * 256) * 8), \
                    16, 0, 0);                                                     \
            }                                                                      \
        } while (0)

    // prologue: stage tile 0, drain, then 2-phase pipeline
    STAGE(0, 0);
    __syncthreads();
    int cur = 0;
    for (int kt = 0; kt < D_DIM / 32; ++kt) {
        if (kt + 1 < D_DIM / 32) STAGE(cur ^ 1, kt + 1);   // prefetch next tile

        bf16x8 af[4], bfr[4];
        #pragma unroll
        for (int m = 0; m < 4; ++m)
            af[m] = *(const bf16x8*)(As[cur] + (lrow_a + m * 16) * 32 + kgrp);
        #pragma unroll
        for (int n = 0; n < 4; ++n)
            bfr[n] = *(const bf16x8*)(Bs[cur] + (lrow_b + n * 16) * 32 + kgrp);

        #pragma unroll
        for (int m = 0; m < 4; ++m)
            #pragma unroll
            for (int n = 0; n < 4; ++n)
                acc[m][n] = __builtin_amdgcn_mfma_f32_16x16x32_bf16(af[m], bfr[n], acc[m][n], 0, 0, 0);

        __syncthreads();   // drains vmcnt(0) (prefetch landed) + lgkmcnt
        cur ^= 1;
    }
    #undef STAGE

    // Epilogue: e = exp(2s) (diag masked); positives at gcol-grow==B;
    // row sums into denom[row]; col sums into denom[col] for off-diag blocks.
    const int colbase = col0 + wc * 64 + (lane & 15);
    float cs[4] = {0.f, 0.f, 0.f, 0.f};   // per-lane column partials (n=0..3)
    #pragma unroll
    for (int m = 0; m < 4; ++m) {
        const int rowbase = row0 + wr * 64 + m * 16 + (lane >> 4) * 4;
        float rs[4] = {0.f, 0.f, 0.f, 0.f};
        #pragma unroll
        for (int n = 0; n < 4; ++n) {
            const int gcol = colbase + n * 16;
            #pragma unroll
            for (int j = 0; j < 4; ++j) {
                const int grow = rowbase + j;
                const float s2 = 2.0f * acc[m][n][j];   // sim / T,  T = 0.5
                const float e  = (grow == gcol) ? 0.0f : __expf(s2);
                if (gcol - grow == B_ROWS) {            // +B diagonal (once per pair)
                    pos[grow] = s2;
                    pos[gcol] = s2;
                }
                rs[j] += e;
                cs[n] += e;
            }
        }
        #pragma unroll
        for (int off = 1; off < 16; off <<= 1) {
            rs[0] += __shfl_xor(rs[0], off);
            rs[1] += __shfl_xor(rs[1], off);
            rs[2] += __shfl_xor(rs[2], off);
            rs[3] += __shfl_xor(rs[3], off);
        }
        if ((lane & 15) == 0) {
            atomicAdd(&denom[rowbase + 0], rs[0]);
            atomicAdd(&denom[rowbase + 1], rs[1]);
            atomicAdd(&denom[rowbase + 2], rs[2]);
            atomicAdd(&denom[rowbase + 3], rs[3]);
        }
    }
    if (offdiag) {
        // reduce column partials across the 4 row-subgroups (lanes ^16, ^32)
        #pragma unroll
        for (int off = 16; off < 64; off <<= 1) {
            cs[0] += __shfl_xor(cs[0], off);
            cs[1] += __shfl_xor(cs[1], off);
            cs[2] += __shfl_xor(cs[2], off);
            cs[3] += __shfl_xor(cs[3], off);
        }
        if (lane < 16) {
            atomicAdd(&denom[colbase + 0],  cs[0]);
            atomicAdd(&denom[colbase + 16], cs[1]);
            atomicAdd(&denom[colbase + 32], cs[2]);
            atomicAdd(&denom[colbase + 48], cs[3]);
        }
    }
}

// ---------------------------------------------------------------------------
// Kernel 3: loss = mean( log(denom + 1e-8) - pos )
// ---------------------------------------------------------------------------
__global__ void loss_kernel(const float* __restrict__ denom,
                            const float* __restrict__ pos,
                            float* __restrict__ out) {
    const int t = threadIdx.x;      // 1024 threads
    float partial = 0.f;
    for (int i = t; i < N2; i += 1024)
        partial += logf(denom[i] + 1e-8f) - pos[i];
    #pragma unroll
    for (int off = 1; off < 64; off <<= 1) partial += __shfl_xor(partial, off);
    __shared__ float red[16];
    if ((t & 63) == 0) red[t >> 6] = partial;
    __syncthreads();
    if (t == 0) {
        float s = 0.f;
        #pragma unroll
        for (int i = 0; i < 16; ++i) s += red[i];
        out[0] = s * (1.0f / (float)N2);
    }
}

// ---------------------------------------------------------------------------
extern "C" void kernel_launch(void* const* d_in, const int* in_sizes, int n_in,
                              void* d_out, int out_size, void* d_ws, size_t ws_size,
                              hipStream_t stream) {
    const float* zi = (const float*)d_in[0];
    const float* zj = (const float*)d_in[1];
    char* ws = (char*)d_ws;
    ushort* zn   = (ushort*)ws;                              // 8192*512 bf16 = 8 MB
    float* denom = (float*)(ws + (size_t)N2 * D_DIM * 2);    // 8192 f32
    float* pos   = denom + N2;                               // 8192 f32
    float* out   = (float*)d_out;

    normalize_kernel<<<N2, 256, 0, stream>>>(zi, zj, zn, denom);
    gram_kernel<<<NTRI, 256, 0, stream>>>(zn, denom, pos);
    loss_kernel<<<1, 1024, 0, stream>>>(denom, pos, out);
}

// Round 7
// 125.103 us; speedup vs baseline: 1.9985x; 1.2176x over previous
//
#include <hip/hip_runtime.h>
#include <hip/hip_bf16.h>
#include <stdint.h>

#define B_ROWS 4096
#define D_DIM  512
#define N2     8192
#define NBLK   64          // 8192 / 128
#define NTRI   (NBLK * (NBLK + 1) / 2)   // 2080 upper-tri blocks (2080 % 8 == 0)

typedef __attribute__((ext_vector_type(8))) short bf16x8;
typedef __attribute__((ext_vector_type(4))) float f32x4;

// ---------------------------------------------------------------------------
// Kernel 1: row L2-norms, normalize, cast to bf16. Also zeroes denom[row].
// ---------------------------------------------------------------------------
__global__ void normalize_kernel(const float* __restrict__ zi,
                                 const float* __restrict__ zj,
                                 ushort* __restrict__ zn,
                                 float* __restrict__ denom) {
    const int row = blockIdx.x;         // 0..8191
    const int t   = threadIdx.x;        // 256 threads, one float2 each
    if (t == 0) denom[row] = 0.0f;
    const float* src = (row < B_ROWS) ? (zi + (size_t)row * D_DIM)
                                      : (zj + (size_t)(row - B_ROWS) * D_DIM);
    float2 v = ((const float2*)src)[t];
    float ss = v.x * v.x + v.y * v.y;
    #pragma unroll
    for (int off = 1; off < 64; off <<= 1) ss += __shfl_xor(ss, off);
    __shared__ float red[4];
    if ((t & 63) == 0) red[t >> 6] = ss;
    __syncthreads();
    const float tot = red[0] + red[1] + red[2] + red[3];
    const float inv = 1.0f / sqrtf(tot);   // norms ~22.6 >> eps
    __hip_bfloat16 hx = __float2bfloat16(v.x * inv);
    __hip_bfloat16 hy = __float2bfloat16(v.y * inv);
    ushort2 h;
    h.x = *(ushort*)&hx;
    h.y = *(ushort*)&hy;
    ((ushort2*)zn)[(size_t)row * (D_DIM / 2) + t] = h;
}

// ---------------------------------------------------------------------------
// Kernel 2: upper-triangular blocks of S = Zn*Zn^T (bf16 MFMA), fused
// exp / diag-mask / positives / row+col partial sums (symmetry exploited).
// 128x128 tile, BK=32, 4 waves (2x2 of 64x64). Round-2 structure (72.5 us,
// best measured; round-6 dbuf regressed via occupancy).
// Round-7 isolated change: XCD-chunked bijective bid swizzle (T1) so each
// XCD's private L2 sees a contiguous tri-band (low bands ~3MB fit 4MB L2).
// ---------------------------------------------------------------------------
__global__ __launch_bounds__(256) void gram_kernel(const ushort* __restrict__ zn,
                                                   float* __restrict__ denom,
                                                   float* __restrict__ pos) {
    __shared__ ushort As[128 * 32];   // 8 KB
    __shared__ ushort Bs[128 * 32];   // 8 KB

    const int t    = threadIdx.x;
    const int lane = t & 63;
    const int wave = t >> 6;
    const int wr   = wave >> 1;       // wave-row quadrant (0..1)
    const int wc   = wave & 1;        // wave-col quadrant (0..1)

    // XCD-chunked bijective swizzle: hardware round-robins blockIdx across
    // 8 XCDs, so give XCD (g&7) the contiguous tri-range [(g&7)*260, ...).
    const int g   = blockIdx.x;
    const int bid = (g & 7) * (NTRI / 8) + (g >> 3);
    // triangular index -> (bx <= by): rows = bx*128, cols = by*128
    int by = (int)((sqrtf(8.0f * (float)bid + 1.0f) - 1.0f) * 0.5f);
    while ((by * (by + 1)) / 2 > bid) --by;
    while (((by + 1) * (by + 2)) / 2 <= bid) ++by;
    const int bx = bid - (by * (by + 1)) / 2;
    const int row0 = bx * 128;
    const int col0 = by * 128;
    const bool offdiag = (bx != by);

    const int srow = t >> 2;          // staging row within half (0..63)
    const int scol = (t & 3) * 8;     // staging col (ushorts)

    f32x4 acc[4][4];
    #pragma unroll
    for (int m = 0; m < 4; ++m)
        #pragma unroll
        for (int n = 0; n < 4; ++n)
            acc[m][n] = (f32x4){0.f, 0.f, 0.f, 0.f};

    const int lrow_a = wr * 64 + (lane & 15);
    const int lrow_b = wc * 64 + (lane & 15);
    const int kgrp   = (lane >> 4) * 8;

    for (int kt = 0; kt < D_DIM / 32; ++kt) {
        const int k0 = kt * 32;
        #pragma unroll
        for (int half = 0; half < 2; ++half) {
            const int r = srow + half * 64;
            const ushort* gA = zn + (size_t)(row0 + r) * D_DIM + k0 + scol;
            const ushort* gB = zn + (size_t)(col0 + r) * D_DIM + k0 + scol;
            __builtin_amdgcn_global_load_lds(
                (const __attribute__((address_space(1))) void*)gA,
                (__attribute__((address_space(3))) void*)(As + (size_t)(t + half * 256) * 8),
                16, 0, 0);
            __builtin_amdgcn_global_load_lds(
                (const __attribute__((address_space(1))) void*)gB,
                (__attribute__((address_space(3))) void*)(Bs + (size_t)(t + half * 256) * 8),
                16, 0, 0);
        }
        __syncthreads();

        bf16x8 af[4], bfr[4];
        #pragma unroll
        for (int m = 0; m < 4; ++m)
            af[m] = *(const bf16x8*)(As + (lrow_a + m * 16) * 32 + kgrp);
        #pragma unroll
        for (int n = 0; n < 4; ++n)
            bfr[n] = *(const bf16x8*)(Bs + (lrow_b + n * 16) * 32 + kgrp);

        #pragma unroll
        for (int m = 0; m < 4; ++m)
            #pragma unroll
            for (int n = 0; n < 4; ++n)
                acc[m][n] = __builtin_amdgcn_mfma_f32_16x16x32_bf16(af[m], bfr[n], acc[m][n], 0, 0, 0);
        __syncthreads();
    }

    // Epilogue: e = exp(2s) (diag masked); positives at gcol-grow==B;
    // row sums into denom[row]; col sums into denom[col] for off-diag blocks.
    const int colbase = col0 + wc * 64 + (lane & 15);
    float cs[4] = {0.f, 0.f, 0.f, 0.f};   // per-lane column partials (n=0..3)
    #pragma unroll
    for (int m = 0; m < 4; ++m) {
        const int rowbase = row0 + wr * 64 + m * 16 + (lane >> 4) * 4;
        float rs[4] = {0.f, 0.f, 0.f, 0.f};
        #pragma unroll
        for (int n = 0; n < 4; ++n) {
            const int gcol = colbase + n * 16;
            #pragma unroll
            for (int j = 0; j < 4; ++j) {
                const int grow = rowbase + j;
                const float s2 = 2.0f * acc[m][n][j];   // sim / T,  T = 0.5
                const float e  = (grow == gcol) ? 0.0f : __expf(s2);
                if (gcol - grow == B_ROWS) {            // +B diagonal (once per pair)
                    pos[grow] = s2;
                    pos[gcol] = s2;
                }
                rs[j] += e;
                cs[n] += e;
            }
        }
        #pragma unroll
        for (int off = 1; off < 16; off <<= 1) {
            rs[0] += __shfl_xor(rs[0], off);
            rs[1] += __shfl_xor(rs[1], off);
            rs[2] += __shfl_xor(rs[2], off);
            rs[3] += __shfl_xor(rs[3], off);
        }
        if ((lane & 15) == 0) {
            atomicAdd(&denom[rowbase + 0], rs[0]);
            atomicAdd(&denom[rowbase + 1], rs[1]);
            atomicAdd(&denom[rowbase + 2], rs[2]);
            atomicAdd(&denom[rowbase + 3], rs[3]);
        }
    }
    if (offdiag) {
        // reduce column partials across the 4 row-subgroups (lanes ^16, ^32)
        #pragma unroll
        for (int off = 16; off < 64; off <<= 1) {
            cs[0] += __shfl_xor(cs[0], off);
            cs[1] += __shfl_xor(cs[1], off);
            cs[2] += __shfl_xor(cs[2], off);
            cs[3] += __shfl_xor(cs[3], off);
        }
        if (lane < 16) {
            atomicAdd(&denom[colbase + 0],  cs[0]);
            atomicAdd(&denom[colbase + 16], cs[1]);
            atomicAdd(&denom[colbase + 32], cs[2]);
            atomicAdd(&denom[colbase + 48], cs[3]);
        }
    }
}

// ---------------------------------------------------------------------------
// Kernel 3: loss = mean( log(denom + 1e-8) - pos )
// ---------------------------------------------------------------------------
__global__ void loss_kernel(const float* __restrict__ denom,
                            const float* __restrict__ pos,
                            float* __restrict__ out) {
    const int t = threadIdx.x;      // 1024 threads
    float partial = 0.f;
    for (int i = t; i < N2; i += 1024)
        partial += logf(denom[i] + 1e-8f) - pos[i];
    #pragma unroll
    for (int off = 1; off < 64; off <<= 1) partial += __shfl_xor(partial, off);
    __shared__ float red[16];
    if ((t & 63) == 0) red[t >> 6] = partial;
    __syncthreads();
    if (t == 0) {
        float s = 0.f;
        #pragma unroll
        for (int i = 0; i < 16; ++i) s += red[i];
        out[0] = s * (1.0f / (float)N2);
    }
}

// ---------------------------------------------------------------------------
extern "C" void kernel_launch(void* const* d_in, const int* in_sizes, int n_in,
                              void* d_out, int out_size, void* d_ws, size_t ws_size,
                              hipStream_t stream) {
    const float* zi = (const float*)d_in[0];
    const float* zj = (const float*)d_in[1];
    char* ws = (char*)d_ws;
    ushort* zn   = (ushort*)ws;                              // 8192*512 bf16 = 8 MB
    float* denom = (float*)(ws + (size_t)N2 * D_DIM * 2);    // 8192 f32
    float* pos   = denom + N2;                               // 8192 f32
    float* out   = (float*)d_out;

    normalize_kernel<<<N2, 256, 0, stream>>>(zi, zj, zn, denom);
    gram_kernel<<<NTRI, 256, 0, stream>>>(zn, denom, pos);
    loss_kernel<<<1, 1024, 0, stream>>>(denom, pos, out);
}